// Round 7
// baseline (1876.646 us; speedup 1.0000x reference)
//
#include <hip/hip_runtime.h>
#include <hip/hip_cooperative_groups.h>

// Problem constants: B=256, T=512, I=256, H=1024, O=128
constexpr int kB = 256;
constexpr int kT = 512;
constexpr int kI = 256;
constexpr int kH = 1024;
constexpr int kO = 128;

constexpr int kG   = 128;            // workgroups in cooperative kernel
constexpr int kNH  = kH / kG;        // 8 h-outputs owned per WG (2 per wave)

typedef float f32x4 __attribute__((ext_vector_type(4)));
typedef unsigned int u32x4 __attribute__((ext_vector_type(4)));

// ---------------------------------------------------------------------------
// XP[b, j] = Bih[j] + dot(inputs[b, T-1, :], Wih[j, :])   for j in [0, 2H)
// Only row t=511 matters (scan emits h_new[-1]; rows of h evolve
// independently). grid=256 (1 batch/block) for full occupancy; Wih re-reads
// stay L2-resident (~2 MB/XCD).
// ---------------------------------------------------------------------------
__global__ void xp_kernel(const float* __restrict__ inputs,
                          const float* __restrict__ Wih,
                          const float* __restrict__ Bih,
                          float* __restrict__ XP) {
    __shared__ __align__(16) float xs[kI];
    const int b   = blockIdx.x;         // grid = 256
    const int tid = threadIdx.x;        // 256
    xs[tid] = inputs[(size_t)b * (kT * kI) + (size_t)(kT - 1) * kI + tid];
    __syncthreads();
    #pragma unroll
    for (int r = 0; r < 8; ++r) {
        const int j = r * 256 + tid;
        const float4* wrow = reinterpret_cast<const float4*>(Wih + (size_t)j * kI);
        const float4* xv   = reinterpret_cast<const float4*>(xs);
        float acc = Bih[j];
        #pragma unroll 8
        for (int i = 0; i < kI / 4; ++i) {
            const float4 w = wrow[i];
            const float4 x = xv[i];
            acc += w.x * x.x + w.y * x.y + w.z * x.z + w.w * x.w;
        }
        XP[b * (2 * kH) + j] = acc;
    }
}

// ---------------------------------------------------------------------------
// Persistent recurrence, b = 0..255. Pure per-WAVE dataflow actors:
//  - each h entry is 8B {f32 value, u32 epoch} at the coherence point
//    (sc0 sc1 bypasses the non-coherent L1/L2);
//  - wave w of WG g owns outputs {8g+2w, 8g+2w+1}; lane k holds weight
//    columns [16k,16k+16) of the wave's 4 rows (f0,f1,h0,h1), so the polled
//    registers ARE the dot operands — no LDS, no __syncthreads, no fences;
//  - owner lane publishes both outputs in ONE {v0,tag,v1,tag} 16B store.
// Wave skew is bounded <=1 step: a wave can only reach step s+1 after every
// wave published s+1, i.e. after every wave finished READING step s.
// ---------------------------------------------------------------------------
__global__ void __launch_bounds__(256, 1)
recur_kernel(const float* __restrict__ Whh,
             const float* __restrict__ Bhh,
             const float* __restrict__ XP,
             unsigned long long* __restrict__ hbuf,  // 2 * kH entries, zeroed
             float* __restrict__ lasts) {            // kB * kH floats
    const int tid  = threadIdx.x;
    const int wg   = blockIdx.x;
    const int wave = tid >> 6;          // 0..3
    const int lane = tid & 63;          // 0..63
    const int out0 = wg * kNH + 2 * wave;   // even; wave owns out0, out0+1

    // --- weights: lane k holds cols [16k,16k+16) of rows f0,f1,h0,h1 ---
    f32x4 wf0[4], wf1[4], wh0[4], wh1[4];
    {
        const float* pf0 = Whh + (size_t)out0 * kH + 16 * lane;
        const float* pf1 = Whh + (size_t)(out0 + 1) * kH + 16 * lane;
        const float* ph0 = Whh + (size_t)(kH + out0) * kH + 16 * lane;
        const float* ph1 = Whh + (size_t)(kH + out0 + 1) * kH + 16 * lane;
        asm volatile(
            "global_load_dwordx4 %0, %16, off\n\t"
            "global_load_dwordx4 %1, %16, off offset:16\n\t"
            "global_load_dwordx4 %2, %16, off offset:32\n\t"
            "global_load_dwordx4 %3, %16, off offset:48\n\t"
            "global_load_dwordx4 %4, %17, off\n\t"
            "global_load_dwordx4 %5, %17, off offset:16\n\t"
            "global_load_dwordx4 %6, %17, off offset:32\n\t"
            "global_load_dwordx4 %7, %17, off offset:48\n\t"
            "global_load_dwordx4 %8, %18, off\n\t"
            "global_load_dwordx4 %9, %18, off offset:16\n\t"
            "global_load_dwordx4 %10, %18, off offset:32\n\t"
            "global_load_dwordx4 %11, %18, off offset:48\n\t"
            "global_load_dwordx4 %12, %19, off\n\t"
            "global_load_dwordx4 %13, %19, off offset:16\n\t"
            "global_load_dwordx4 %14, %19, off offset:32\n\t"
            "global_load_dwordx4 %15, %19, off offset:48\n\t"
            "s_waitcnt vmcnt(0)"
            : "=&v"(wf0[0]), "=&v"(wf0[1]), "=&v"(wf0[2]), "=&v"(wf0[3]),
              "=&v"(wf1[0]), "=&v"(wf1[1]), "=&v"(wf1[2]), "=&v"(wf1[3]),
              "=&v"(wh0[0]), "=&v"(wh0[1]), "=&v"(wh0[2]), "=&v"(wh0[3]),
              "=&v"(wh1[0]), "=&v"(wh1[1]), "=&v"(wh1[2]), "=&v"(wh1[3])
            : "v"(pf0), "v"(pf1), "v"(ph0), "v"(ph1));
    }

    // Biases (b-independent, uniform per wave; L2-cached broadcast loads).
    const float bf0 = Bhh[out0];
    const float bf1 = Bhh[out0 + 1];
    const float bh0 = Bhh[kH + out0];
    const float bh1 = Bhh[kH + out0 + 1];

    const int ownLane = out0 >> 4;            // lane holding entries out0,out0+1
    const int selIdx  = (out0 & 15) >> 1;     // which u32x4 holds them (uniform)

    for (int b = 0; b < kB; ++b) {
        const unsigned long long* hsrc = hbuf + (size_t)(b & 1) * kH;
        unsigned long long* hdst       = hbuf + (size_t)((b + 1) & 1) * kH;

        // XP prefetch (uniform address per wave; cached, one transaction).
        const float2 xf2 = *reinterpret_cast<const float2*>(
            XP + (size_t)b * (2 * kH) + out0);
        const float2 xh2 = *reinterpret_cast<const float2*>(
            XP + (size_t)b * (2 * kH) + kH + out0);

        // --- poll: lane k re-loads its 16 entries until all tags == b ---
        u32x4 A[8];
        {
            const unsigned long long* pp = hsrc + (size_t)lane * 16;
            const unsigned expt = (unsigned)b;
            while (true) {
                asm volatile(
                    "global_load_dwordx4 %0, %8, off sc0 sc1\n\t"
                    "global_load_dwordx4 %1, %8, off offset:16 sc0 sc1\n\t"
                    "global_load_dwordx4 %2, %8, off offset:32 sc0 sc1\n\t"
                    "global_load_dwordx4 %3, %8, off offset:48 sc0 sc1\n\t"
                    "global_load_dwordx4 %4, %8, off offset:64 sc0 sc1\n\t"
                    "global_load_dwordx4 %5, %8, off offset:80 sc0 sc1\n\t"
                    "global_load_dwordx4 %6, %8, off offset:96 sc0 sc1\n\t"
                    "global_load_dwordx4 %7, %8, off offset:112 sc0 sc1\n\t"
                    "s_waitcnt vmcnt(0)"
                    : "=&v"(A[0]), "=&v"(A[1]), "=&v"(A[2]), "=&v"(A[3]),
                      "=&v"(A[4]), "=&v"(A[5]), "=&v"(A[6]), "=&v"(A[7])
                    : "v"(pp) : "memory");
                unsigned bad = 0;
                #pragma unroll
                for (int m = 0; m < 8; ++m)
                    bad |= (A[m].y ^ expt) | (A[m].w ^ expt);
                if (!__any(bad != 0)) break;
                __builtin_amdgcn_s_sleep(1);   // throttle spin L3 traffic
            }
        }

        // --- dot: polled regs are the operands; 64 FMA/lane, all static ---
        float p0 = 0.f, p1 = 0.f, p2 = 0.f, p3 = 0.f;
        #pragma unroll
        for (int m = 0; m < 8; ++m) {
            const float v0 = __uint_as_float(A[m].x);
            const float v1 = __uint_as_float(A[m].z);
            const int c0 = (2 * m) & 3, c1 = (2 * m + 1) & 3, q = m >> 1;
            p0 += wf0[q][c0] * v0 + wf0[q][c1] * v1;
            p1 += wf1[q][c0] * v0 + wf1[q][c1] * v1;
            p2 += wh0[q][c0] * v0 + wh0[q][c1] * v1;
            p3 += wh1[q][c0] * v0 + wh1[q][c1] * v1;
        }

        // hprev for out0/out1: 8-way static select (uniform selIdx per wave);
        // only ownLane's values are meaningful.
        float hp0 = 0.f, hp1 = 0.f;
        #pragma unroll
        for (int m = 0; m < 8; ++m) {
            if (selIdx == m) {
                hp0 = __uint_as_float(A[m].x);
                hp1 = __uint_as_float(A[m].z);
            }
        }

        // --- 6-stage x 4-value butterfly reduce across the wave ---
        #pragma unroll
        for (int m = 1; m < 64; m <<= 1) {
            p0 += __shfl_xor(p0, m);
            p1 += __shfl_xor(p1, m);
            p2 += __shfl_xor(p2, m);
            p3 += __shfl_xor(p3, m);
        }

        // --- owner lane: gates + single {v0,tag,v1,tag} publish ---
        if (lane == ownLane) {
            const float z10 = xf2.x + p0 + bf0;
            const float z11 = xf2.y + p1 + bf1;
            const float fG0 = 1.0f / (1.0f + __expf(-z10));
            const float fG1 = 1.0f / (1.0f + __expf(-z11));
            const float z20 = xh2.x + fG0 * (p2 + bh0);
            const float z21 = xh2.y + fG1 * (p3 + bh1);
            const float a0 = fabsf(z20), a1 = fabsf(z21);
            const float hG0 = copysignf(1.0f - 2.0f / (__expf(2.0f * a0) + 1.0f), z20);
            const float hG1 = copysignf(1.0f - 2.0f / (__expf(2.0f * a1) + 1.0f), z21);
            const float hn0 = (1.0f - fG0) * hp0 + fG0 * hG0;
            const float hn1 = (1.0f - fG1) * hp1 + fG1 * hG1;
            u32x4 pk;
            pk.x = __float_as_uint(hn0); pk.y = (unsigned)(b + 1);
            pk.z = __float_as_uint(hn1); pk.w = (unsigned)(b + 1);
            asm volatile("global_store_dwordx4 %0, %1, off sc0 sc1"
                         :: "v"(hdst + out0), "v"(pk) : "memory");
            float2 ln; ln.x = hn0; ln.y = hn1;
            *reinterpret_cast<float2*>(lasts + (size_t)b * kH + out0) = ln;
        }
        // No barrier: the next step's poll self-synchronizes on the tags.
    }
}

// ---------------------------------------------------------------------------
// out[b, o] = Bout[o] + dot(lasts[b, :], Wout[o, :]); grid=256, 1 batch/block.
// ---------------------------------------------------------------------------
__global__ void out_kernel(const float* __restrict__ lasts,
                           const float* __restrict__ Wout,
                           const float* __restrict__ Bout,
                           float* __restrict__ out) {
    __shared__ __align__(16) float ls[kH];
    const int b   = blockIdx.x;         // grid = 256
    const int tid = threadIdx.x;        // 128
    #pragma unroll
    for (int r = 0; r < kH / 128; ++r)
        ls[tid + r * 128] = lasts[(size_t)b * kH + tid + r * 128];
    __syncthreads();
    const float4* wrow = reinterpret_cast<const float4*>(Wout + (size_t)tid * kH);
    const float4* lv   = reinterpret_cast<const float4*>(ls);
    float acc = Bout[tid];
    #pragma unroll 8
    for (int i = 0; i < kH / 4; ++i) {
        const float4 w = wrow[i];
        const float4 x = lv[i];
        acc += w.x * x.x + w.y * x.y + w.z * x.z + w.w * x.w;
    }
    out[b * kO + tid] = acc;
}

extern "C" void kernel_launch(void* const* d_in, const int* in_sizes, int n_in,
                              void* d_out, int out_size, void* d_ws, size_t ws_size,
                              hipStream_t stream) {
    const float* inputs = (const float*)d_in[0];
    const float* Wih    = (const float*)d_in[1];
    const float* Whh    = (const float*)d_in[2];
    const float* Bih    = (const float*)d_in[3];
    const float* Bhh    = (const float*)d_in[4];
    const float* Wout   = (const float*)d_in[5];
    const float* Bout   = (const float*)d_in[6];
    float* out = (float*)d_out;

    char* ws = (char*)d_ws;
    float* XP    = (float*)(ws);                                   // 256*2048 f32 = 2 MiB
    float* lasts = (float*)(ws + (size_t)kB * 2 * kH * 4);         // 256*1024 f32 = 1 MiB
    unsigned long long* hbuf = (unsigned long long*)
        (ws + (size_t)kB * 2 * kH * 4 + (size_t)kB * kH * 4);      // 2*kH x 8B = 16 KiB

    // hbuf = {h=0, tag=0}: step 0 reads zeros with epoch 0.
    hipMemsetAsync(hbuf, 0, 2 * kH * sizeof(unsigned long long), stream);

    xp_kernel<<<dim3(kB), dim3(256), 0, stream>>>(inputs, Wih, Bih, XP);

    void* args[] = { (void*)&Whh, (void*)&Bhh, (void*)&XP,
                     (void*)&hbuf, (void*)&lasts };
    hipLaunchCooperativeKernel((void*)recur_kernel, dim3(kG), dim3(256),
                               args, 0, stream);

    out_kernel<<<dim3(kB), dim3(128), 0, stream>>>(lasts, Wout, Bout, out);
}

// Round 8
// 771.943 us; speedup vs baseline: 2.4311x; 2.4311x over previous
//
#include <hip/hip_runtime.h>
#include <hip/hip_cooperative_groups.h>

// Problem constants: B=256, T=512, I=256, H=1024, O=128
constexpr int kB = 256;
constexpr int kT = 512;
constexpr int kI = 256;
constexpr int kH = 1024;
constexpr int kO = 128;

constexpr int kG   = 128;            // workgroups in cooperative kernel
constexpr int kNH  = kH / kG;        // 8 h-outputs owned per WG (1 per 32-lane group)

typedef float f32x4 __attribute__((ext_vector_type(4)));
typedef unsigned int u32x2 __attribute__((ext_vector_type(2)));
typedef unsigned int u32x4 __attribute__((ext_vector_type(4)));

__device__ __forceinline__ int padidx(int i) { return i + ((i >> 6) << 2); }

// ---------------------------------------------------------------------------
// XP[b, j] = Bih[j] + dot(inputs[b, T-1, :], Wih[j, :])   for j in [0, 2H)
// Only row t=511 matters (scan emits h_new[-1]; rows of h evolve
// independently). grid=256 (1 batch/block) for full occupancy; Wih re-reads
// are L2-resident (2 MB).
// ---------------------------------------------------------------------------
__global__ void xp_kernel(const float* __restrict__ inputs,
                          const float* __restrict__ Wih,
                          const float* __restrict__ Bih,
                          float* __restrict__ XP) {
    __shared__ __align__(16) float xs[kI];
    const int b   = blockIdx.x;         // grid = 256
    const int tid = threadIdx.x;        // 256
    xs[tid] = inputs[(size_t)b * (kT * kI) + (size_t)(kT - 1) * kI + tid];
    __syncthreads();
    #pragma unroll
    for (int r = 0; r < 8; ++r) {
        const int j = r * 256 + tid;
        const float4* wrow = reinterpret_cast<const float4*>(Wih + (size_t)j * kI);
        const float4* xv   = reinterpret_cast<const float4*>(xs);
        float acc = Bih[j];
        #pragma unroll 8
        for (int i = 0; i < kI / 4; ++i) {
            const float4 w = wrow[i];
            const float4 x = xv[i];
            acc += w.x * x.x + w.y * x.y + w.z * x.z + w.w * x.w;
        }
        XP[b * (2 * kH) + j] = acc;
    }
}

// ---------------------------------------------------------------------------
// Persistent recurrence, b = 0..255. Cooperative dataflow sync (round-3
// protocol: 8B {f32 value, u32 epoch} entries at the coherence point via
// sc0 sc1; each thread polls only ITS 4 entries -> ~1 MB per grid poll
// round, which L3 sustains) + single-barrier intra-WG structure:
//   poll(4 entries) -> LDS stage -> __syncthreads ->
//   group g (32 lanes) computes f-dot AND h-dot for output hd=wg*8+g
//   (64 FMA/lane over its 32-elem chunk) -> 5-stage shfl_xor reduce
//   (stays within 32-lane groups) -> lane 0: gates + ONE 8B publish.
// No dres LDS round trip, no second barrier. LDS reuse is safe: passing
// poll b+1 implies all WGs published b+1, which implies every group's
// ds_reads of step b retired (publish depends on them).
// ---------------------------------------------------------------------------
__global__ void __launch_bounds__(256, 1)
recur_kernel(const float* __restrict__ Whh,
             const float* __restrict__ Bhh,
             const float* __restrict__ XP,
             unsigned long long* __restrict__ hbuf,  // 2 * kH entries, zeroed
             float* __restrict__ lasts) {            // kB * kH floats
    const int tid = threadIdx.x;
    const int wg  = blockIdx.x;
    const int g   = tid >> 5;           // 0..7: output group
    const int j   = tid & 31;           // lane within group
    const int hd  = wg * kNH + g;       // this group's output index

    // --- weights: lane j holds elements [32j,32j+32) of rows hd (f) and
    //     kH+hd (h): 16 x f32x4 = 64 fp32, pinned via opaque asm loads ---
    f32x4 wf[8], wh[8];
    {
        const float* pf = Whh + (size_t)hd * kH + 32 * j;
        const float* ph = Whh + (size_t)(kH + hd) * kH + 32 * j;
        asm volatile(
            "global_load_dwordx4 %0, %16, off\n\t"
            "global_load_dwordx4 %1, %16, off offset:16\n\t"
            "global_load_dwordx4 %2, %16, off offset:32\n\t"
            "global_load_dwordx4 %3, %16, off offset:48\n\t"
            "global_load_dwordx4 %4, %16, off offset:64\n\t"
            "global_load_dwordx4 %5, %16, off offset:80\n\t"
            "global_load_dwordx4 %6, %16, off offset:96\n\t"
            "global_load_dwordx4 %7, %16, off offset:112\n\t"
            "global_load_dwordx4 %8, %17, off\n\t"
            "global_load_dwordx4 %9, %17, off offset:16\n\t"
            "global_load_dwordx4 %10, %17, off offset:32\n\t"
            "global_load_dwordx4 %11, %17, off offset:48\n\t"
            "global_load_dwordx4 %12, %17, off offset:64\n\t"
            "global_load_dwordx4 %13, %17, off offset:80\n\t"
            "global_load_dwordx4 %14, %17, off offset:96\n\t"
            "global_load_dwordx4 %15, %17, off offset:112\n\t"
            "s_waitcnt vmcnt(0)"
            : "=&v"(wf[0]), "=&v"(wf[1]), "=&v"(wf[2]), "=&v"(wf[3]),
              "=&v"(wf[4]), "=&v"(wf[5]), "=&v"(wf[6]), "=&v"(wf[7]),
              "=&v"(wh[0]), "=&v"(wh[1]), "=&v"(wh[2]), "=&v"(wh[3]),
              "=&v"(wh[4]), "=&v"(wh[5]), "=&v"(wh[6]), "=&v"(wh[7])
            : "v"(pf), "v"(ph));
    }

    // Biases (b-independent; only lane 0's values are used).
    const float bf = Bhh[hd];
    const float bh = Bhh[kH + hd];

    // Padded LDS: element i lives at i + 4*(i/64). Each 32-elem chunk is
    // contiguous (pads fall on 64-boundaries); 16B-aligned for b128.
    __shared__ __align__(16) float sh[kH + 64];

    for (int b = 0; b < kB; ++b) {
        const unsigned long long* hsrc = hbuf + (size_t)(b & 1) * kH;
        unsigned long long* hdst       = hbuf + (size_t)((b + 1) & 1) * kH;

        // XP prefetch (L2-warm; used by lane 0 at the end of the step).
        float xf = 0.f, xh = 0.f;
        if (j == 0) {
            xf = XP[b * (2 * kH) + hd];
            xh = XP[b * (2 * kH) + kH + hd];
        }

        // --- cooperative poll: this thread's 4 entries until tags == b ---
        u32x4 A, C;
        {
            const unsigned long long* pollp = hsrc + (size_t)tid * 4;
            const unsigned expt = (unsigned)b;
            do {
                asm volatile(
                    "global_load_dwordx4 %0, %2, off sc0 sc1\n\t"
                    "global_load_dwordx4 %1, %2, off offset:16 sc0 sc1\n\t"
                    "s_waitcnt vmcnt(0)"
                    : "=v"(A), "=v"(C) : "v"(pollp) : "memory");
            } while (A.y != expt || A.w != expt || C.y != expt || C.w != expt);
        }
        // Stage the 4 values into LDS (padded; 4t never crosses a pad).
        {
            f32x4 hv;
            hv.x = __uint_as_float(A.x);
            hv.y = __uint_as_float(A.z);
            hv.z = __uint_as_float(C.x);
            hv.w = __uint_as_float(C.z);
            *reinterpret_cast<f32x4*>(&sh[padidx(tid * 4)]) = hv;
        }
        __syncthreads();   // the ONLY barrier per step

        // --- both dots over this lane's 32-element chunk ---
        const f32x4* shv = reinterpret_cast<const f32x4*>(&sh[padidx(32 * j)]);
        float pf = 0.f, ph = 0.f;
        #pragma unroll
        for (int m = 0; m < 8; ++m) {
            const f32x4 h4 = shv[m];
            pf += wf[m].x * h4.x + wf[m].y * h4.y + wf[m].z * h4.z + wf[m].w * h4.w;
            ph += wh[m].x * h4.x + wh[m].y * h4.y + wh[m].z * h4.z + wh[m].w * h4.w;
        }
        // hprev for this group's output (any lane may read; used by lane 0).
        const float hprev = sh[padidx(hd)];

        // --- 5-stage butterfly within the 32-lane group (masks < 32) ---
        #pragma unroll
        for (int m = 1; m < 32; m <<= 1) {
            pf += __shfl_xor(pf, m);
            ph += __shfl_xor(ph, m);
        }

        // --- lane 0 of each group: gates + single {value, epoch} publish ---
        if (j == 0) {
            const float z1 = xf + pf + bf;
            const float fG = 1.0f / (1.0f + __expf(-z1));
            const float z2 = xh + fG * (ph + bh);
            const float az = fabsf(z2);
            const float hG = copysignf(1.0f - 2.0f / (__expf(2.0f * az) + 1.0f), z2);
            const float hnew = (1.0f - fG) * hprev + fG * hG;
            u32x2 pk;
            pk.x = __float_as_uint(hnew);
            pk.y = (unsigned)(b + 1);
            asm volatile("global_store_dwordx2 %0, %1, off sc0 sc1"
                         :: "v"(hdst + hd), "v"(pk) : "memory");
            lasts[(size_t)b * kH + hd] = hnew;   // cached; read by out_kernel
        }
        // No trailing barrier: the next poll self-synchronizes on the tags.
    }
}

// ---------------------------------------------------------------------------
// out[b, o] = Bout[o] + dot(lasts[b, :], Wout[o, :]); grid=256, 1 batch/block.
// ---------------------------------------------------------------------------
__global__ void out_kernel(const float* __restrict__ lasts,
                           const float* __restrict__ Wout,
                           const float* __restrict__ Bout,
                           float* __restrict__ out) {
    __shared__ __align__(16) float ls[kH];
    const int b   = blockIdx.x;         // grid = 256
    const int tid = threadIdx.x;        // 128
    #pragma unroll
    for (int r = 0; r < kH / 128; ++r)
        ls[tid + r * 128] = lasts[(size_t)b * kH + tid + r * 128];
    __syncthreads();
    const float4* wrow = reinterpret_cast<const float4*>(Wout + (size_t)tid * kH);
    const float4* lv   = reinterpret_cast<const float4*>(ls);
    float acc = Bout[tid];
    #pragma unroll 8
    for (int i = 0; i < kH / 4; ++i) {
        const float4 w = wrow[i];
        const float4 x = lv[i];
        acc += w.x * x.x + w.y * x.y + w.z * x.z + w.w * x.w;
    }
    out[b * kO + tid] = acc;
}

extern "C" void kernel_launch(void* const* d_in, const int* in_sizes, int n_in,
                              void* d_out, int out_size, void* d_ws, size_t ws_size,
                              hipStream_t stream) {
    const float* inputs = (const float*)d_in[0];
    const float* Wih    = (const float*)d_in[1];
    const float* Whh    = (const float*)d_in[2];
    const float* Bih    = (const float*)d_in[3];
    const float* Bhh    = (const float*)d_in[4];
    const float* Wout   = (const float*)d_in[5];
    const float* Bout   = (const float*)d_in[6];
    float* out = (float*)d_out;

    char* ws = (char*)d_ws;
    float* XP    = (float*)(ws);                                   // 256*2048 f32 = 2 MiB
    float* lasts = (float*)(ws + (size_t)kB * 2 * kH * 4);         // 256*1024 f32 = 1 MiB
    unsigned long long* hbuf = (unsigned long long*)
        (ws + (size_t)kB * 2 * kH * 4 + (size_t)kB * kH * 4);      // 2*kH x 8B = 16 KiB

    // hbuf = {h=0, tag=0}: step 0 reads zeros with epoch 0.
    hipMemsetAsync(hbuf, 0, 2 * kH * sizeof(unsigned long long), stream);

    xp_kernel<<<dim3(kB), dim3(256), 0, stream>>>(inputs, Wih, Bih, XP);

    void* args[] = { (void*)&Whh, (void*)&Bhh, (void*)&XP,
                     (void*)&hbuf, (void*)&lasts };
    hipLaunchCooperativeKernel((void*)recur_kernel, dim3(kG), dim3(256),
                               args, 0, stream);

    out_kernel<<<dim3(kB), dim3(128), 0, stream>>>(lasts, Wout, Bout, out);
}

// Round 10
// 737.965 us; speedup vs baseline: 2.5430x; 1.0460x over previous
//
#include <hip/hip_runtime.h>

// Problem constants: B=256, T=512, I=256, H=1024, O=128
constexpr int kB = 256;
constexpr int kT = 512;
constexpr int kI = 256;
constexpr int kH = 1024;
constexpr int kO = 128;

constexpr int kG   = 128;            // workgroups in persistent kernel
constexpr int kNH  = kH / kG;        // 8 h-outputs owned per WG (1 per 32-lane group)

typedef float f32x4 __attribute__((ext_vector_type(4)));
typedef unsigned int u32x2 __attribute__((ext_vector_type(2)));
typedef unsigned int u32x4 __attribute__((ext_vector_type(4)));

__device__ __forceinline__ int padidx(int i) { return i + ((i >> 6) << 2); }

// ---------------------------------------------------------------------------
// XP[b, j] = Bih[j] + dot(inputs[b, T-1, :], Wih[j, :])   for j in [0, 2H)
// Only row t=511 matters (scan emits h_new[-1]; rows of h evolve
// independently). grid=256 (1 batch/block) for full occupancy; Wih re-reads
// are L2-resident (2 MB).
// ---------------------------------------------------------------------------
__global__ void xp_kernel(const float* __restrict__ inputs,
                          const float* __restrict__ Wih,
                          const float* __restrict__ Bih,
                          float* __restrict__ XP) {
    __shared__ __align__(16) float xs[kI];
    const int b   = blockIdx.x;         // grid = 256
    const int tid = threadIdx.x;        // 256
    xs[tid] = inputs[(size_t)b * (kT * kI) + (size_t)(kT - 1) * kI + tid];
    __syncthreads();
    #pragma unroll
    for (int r = 0; r < 8; ++r) {
        const int j = r * 256 + tid;
        const float4* wrow = reinterpret_cast<const float4*>(Wih + (size_t)j * kI);
        const float4* xv   = reinterpret_cast<const float4*>(xs);
        float acc = Bih[j];
        #pragma unroll 8
        for (int i = 0; i < kI / 4; ++i) {
            const float4 w = wrow[i];
            const float4 x = xv[i];
            acc += w.x * x.x + w.y * x.y + w.z * x.z + w.w * x.w;
        }
        XP[b * (2 * kH) + j] = acc;
    }
}

// ---------------------------------------------------------------------------
// Persistent recurrence, b = 0..255. Cooperative dataflow sync (8B
// {f32 value, u32 epoch} entries at the coherence point via sc0 sc1; each
// thread polls only ITS 4 entries -> ~1 MB per grid poll round) +
// single-barrier intra-WG structure:
//   poll(4 entries) -> LDS stage -> __syncthreads ->
//   group g (32 lanes) computes f-dot AND h-dot for output hd=wg*8+g
//   (64 FMA/lane over its 32-elem chunk) -> 5-stage shfl_xor reduce ->
//   lane 0: gates + ONE 8B publish.
// Launched as a REGULAR kernel: no cooperative API is used (sync is pure
// dataflow); 128 blocks x 4 waves (52 VGPR, 4.6 KB LDS) are all resident on
// 256 CUs by capacity, and step 0 never spins (memset pre-satisfies tag 0),
// so staggered block starts cannot deadlock.
// ---------------------------------------------------------------------------
__global__ void __launch_bounds__(256, 1)
recur_kernel(const float* __restrict__ Whh,
             const float* __restrict__ Bhh,
             const float* __restrict__ XP,
             unsigned long long* __restrict__ hbuf,  // 2 * kH entries, zeroed
             float* __restrict__ lasts) {            // kB * kH floats
    const int tid = threadIdx.x;
    const int wg  = blockIdx.x;
    const int g   = tid >> 5;           // 0..7: output group
    const int j   = tid & 31;           // lane within group
    const int hd  = wg * kNH + g;       // this group's output index

    // --- weights: lane j holds elements [32j,32j+32) of rows hd (f) and
    //     kH+hd (h): 16 x f32x4 = 64 fp32, pinned via opaque asm loads ---
    f32x4 wf[8], wh[8];
    {
        const float* pf = Whh + (size_t)hd * kH + 32 * j;
        const float* ph = Whh + (size_t)(kH + hd) * kH + 32 * j;
        asm volatile(
            "global_load_dwordx4 %0, %16, off\n\t"
            "global_load_dwordx4 %1, %16, off offset:16\n\t"
            "global_load_dwordx4 %2, %16, off offset:32\n\t"
            "global_load_dwordx4 %3, %16, off offset:48\n\t"
            "global_load_dwordx4 %4, %16, off offset:64\n\t"
            "global_load_dwordx4 %5, %16, off offset:80\n\t"
            "global_load_dwordx4 %6, %16, off offset:96\n\t"
            "global_load_dwordx4 %7, %16, off offset:112\n\t"
            "global_load_dwordx4 %8, %17, off\n\t"
            "global_load_dwordx4 %9, %17, off offset:16\n\t"
            "global_load_dwordx4 %10, %17, off offset:32\n\t"
            "global_load_dwordx4 %11, %17, off offset:48\n\t"
            "global_load_dwordx4 %12, %17, off offset:64\n\t"
            "global_load_dwordx4 %13, %17, off offset:80\n\t"
            "global_load_dwordx4 %14, %17, off offset:96\n\t"
            "global_load_dwordx4 %15, %17, off offset:112\n\t"
            "s_waitcnt vmcnt(0)"
            : "=&v"(wf[0]), "=&v"(wf[1]), "=&v"(wf[2]), "=&v"(wf[3]),
              "=&v"(wf[4]), "=&v"(wf[5]), "=&v"(wf[6]), "=&v"(wf[7]),
              "=&v"(wh[0]), "=&v"(wh[1]), "=&v"(wh[2]), "=&v"(wh[3]),
              "=&v"(wh[4]), "=&v"(wh[5]), "=&v"(wh[6]), "=&v"(wh[7])
            : "v"(pf), "v"(ph));
    }

    // Biases (b-independent; only lane 0's values are used).
    const float bf = Bhh[hd];
    const float bh = Bhh[kH + hd];

    // Padded LDS: element i lives at i + 4*(i/64). Each 32-elem chunk is
    // contiguous (pads fall on 64-boundaries); 16B-aligned for b128.
    __shared__ __align__(16) float sh[kH + 64];

    for (int b = 0; b < kB; ++b) {
        const unsigned long long* hsrc = hbuf + (size_t)(b & 1) * kH;
        unsigned long long* hdst       = hbuf + (size_t)((b + 1) & 1) * kH;

        // XP prefetch (L2-warm; used by lane 0 at the end of the step).
        float xf = 0.f, xh = 0.f;
        if (j == 0) {
            xf = XP[b * (2 * kH) + hd];
            xh = XP[b * (2 * kH) + kH + hd];
        }

        // --- cooperative poll: this thread's 4 entries until tags == b ---
        u32x4 A, C;
        {
            const unsigned long long* pollp = hsrc + (size_t)tid * 4;
            const unsigned expt = (unsigned)b;
            do {
                asm volatile(
                    "global_load_dwordx4 %0, %2, off sc0 sc1\n\t"
                    "global_load_dwordx4 %1, %2, off offset:16 sc0 sc1\n\t"
                    "s_waitcnt vmcnt(0)"
                    : "=v"(A), "=v"(C) : "v"(pollp) : "memory");
            } while (A.y != expt || A.w != expt || C.y != expt || C.w != expt);
        }
        // Stage the 4 values into LDS (padded; 4t never crosses a pad).
        {
            f32x4 hv;
            hv.x = __uint_as_float(A.x);
            hv.y = __uint_as_float(A.z);
            hv.z = __uint_as_float(C.x);
            hv.w = __uint_as_float(C.z);
            *reinterpret_cast<f32x4*>(&sh[padidx(tid * 4)]) = hv;
        }
        __syncthreads();   // the ONLY barrier per step

        // --- both dots over this lane's 32-element chunk ---
        const f32x4* shv = reinterpret_cast<const f32x4*>(&sh[padidx(32 * j)]);
        float pf = 0.f, ph = 0.f;
        #pragma unroll
        for (int m = 0; m < 8; ++m) {
            const f32x4 h4 = shv[m];
            pf += wf[m].x * h4.x + wf[m].y * h4.y + wf[m].z * h4.z + wf[m].w * h4.w;
            ph += wh[m].x * h4.x + wh[m].y * h4.y + wh[m].z * h4.z + wh[m].w * h4.w;
        }
        // hprev for this group's output (any lane may read; used by lane 0).
        const float hprev = sh[padidx(hd)];

        // --- 5-stage butterfly within the 32-lane group (masks < 32) ---
        #pragma unroll
        for (int m = 1; m < 32; m <<= 1) {
            pf += __shfl_xor(pf, m);
            ph += __shfl_xor(ph, m);
        }

        // --- lane 0 of each group: gates + single {value, epoch} publish ---
        if (j == 0) {
            const float z1 = xf + pf + bf;
            const float fG = 1.0f / (1.0f + __expf(-z1));
            const float z2 = xh + fG * (ph + bh);
            const float az = fabsf(z2);
            const float hG = copysignf(1.0f - 2.0f / (__expf(2.0f * az) + 1.0f), z2);
            const float hnew = (1.0f - fG) * hprev + fG * hG;
            u32x2 pk;
            pk.x = __float_as_uint(hnew);
            pk.y = (unsigned)(b + 1);
            asm volatile("global_store_dwordx2 %0, %1, off sc0 sc1"
                         :: "v"(hdst + hd), "v"(pk) : "memory");
            lasts[(size_t)b * kH + hd] = hnew;   // cached; read by out_kernel
        }
        // No trailing barrier: the next poll self-synchronizes on the tags.
    }
}

// ---------------------------------------------------------------------------
// out[b, o] = Bout[o] + dot(lasts[b, :], Wout[o, :]); grid=256, 1 batch/block.
// ---------------------------------------------------------------------------
__global__ void out_kernel(const float* __restrict__ lasts,
                           const float* __restrict__ Wout,
                           const float* __restrict__ Bout,
                           float* __restrict__ out) {
    __shared__ __align__(16) float ls[kH];
    const int b   = blockIdx.x;         // grid = 256
    const int tid = threadIdx.x;        // 128
    #pragma unroll
    for (int r = 0; r < kH / 128; ++r)
        ls[tid + r * 128] = lasts[(size_t)b * kH + tid + r * 128];
    __syncthreads();
    const float4* wrow = reinterpret_cast<const float4*>(Wout + (size_t)tid * kH);
    const float4* lv   = reinterpret_cast<const float4*>(ls);
    float acc = Bout[tid];
    #pragma unroll 8
    for (int i = 0; i < kH / 4; ++i) {
        const float4 w = wrow[i];
        const float4 x = lv[i];
        acc += w.x * x.x + w.y * x.y + w.z * x.z + w.w * x.w;
    }
    out[b * kO + tid] = acc;
}

extern "C" void kernel_launch(void* const* d_in, const int* in_sizes, int n_in,
                              void* d_out, int out_size, void* d_ws, size_t ws_size,
                              hipStream_t stream) {
    const float* inputs = (const float*)d_in[0];
    const float* Wih    = (const float*)d_in[1];
    const float* Whh    = (const float*)d_in[2];
    const float* Bih    = (const float*)d_in[3];
    const float* Bhh    = (const float*)d_in[4];
    const float* Wout   = (const float*)d_in[5];
    const float* Bout   = (const float*)d_in[6];
    float* out = (float*)d_out;

    char* ws = (char*)d_ws;
    float* XP    = (float*)(ws);                                   // 256*2048 f32 = 2 MiB
    float* lasts = (float*)(ws + (size_t)kB * 2 * kH * 4);         // 256*1024 f32 = 1 MiB
    unsigned long long* hbuf = (unsigned long long*)
        (ws + (size_t)kB * 2 * kH * 4 + (size_t)kB * kH * 4);      // 2*kH x 8B = 16 KiB

    // hbuf = {h=0, tag=0}: step 0 reads zeros with epoch 0.
    hipMemsetAsync(hbuf, 0, 2 * kH * sizeof(unsigned long long), stream);

    xp_kernel<<<dim3(kB), dim3(256), 0, stream>>>(inputs, Wih, Bih, XP);

    // Regular launch: no cooperative API is used inside the kernel; all 128
    // blocks are resident by capacity and the dataflow protocol cannot
    // deadlock on staggered starts (step-0 tags are pre-satisfied).
    recur_kernel<<<dim3(kG), dim3(256), 0, stream>>>(Whh, Bhh, XP, hbuf, lasts);

    out_kernel<<<dim3(kB), dim3(128), 0, stream>>>(lasts, Wout, Bout, out);
}